// Round 3
// baseline (1946.636 us; speedup 1.0000x reference)
//
#include <hip/hip_runtime.h>

// HybridStateSpaceAttention on MI355X (gfx950).
// Workspace footprint: 240 MB (gated on ws_size; if insufficient we launch
// nothing -> clean absmax failure instead of a GPU fault).
//
// Order: casts/transposes -> global attn (comp gemm, logits, softmax, PV)
//  -> SWA per (batch,window): QK gemm -> softmax -> PV gemm (tri/wsum in
//     epilogue, odd windows accumulate) -> cast local
//  -> mw gemm(sigmoid) -> bcast_small -> bcast_big (in-place) -> mixed
//  -> out gemm(+bias)

#define DEV __device__ __forceinline__

typedef float f4 __attribute__((ext_vector_type(4)));
typedef float f32x4 __attribute__((ext_vector_type(4)));
typedef unsigned short u16x4 __attribute__((ext_vector_type(4)));
typedef unsigned short u16x8 __attribute__((ext_vector_type(8)));
typedef __bf16 bf16x8 __attribute__((ext_vector_type(8)));

DEV unsigned short f2bf(float f) {
  unsigned u = __float_as_uint(f);
  return (unsigned short)((u + 0x7FFFu + ((u >> 16) & 1u)) >> 16);
}
DEV float bf2f(unsigned short h) { return __uint_as_float(((unsigned)h) << 16); }

DEV float block_sum_256(float v) {
  #pragma unroll
  for (int o = 32; o > 0; o >>= 1) v += __shfl_down(v, o, 64);
  __shared__ float sw[4];
  if ((threadIdx.x & 63) == 0) sw[threadIdx.x >> 6] = v;
  __syncthreads();
  return sw[0] + sw[1] + sw[2] + sw[3];
}

// ---------------------------------------------------------------- GEMM (NT)
// C[m][n] = sum_k A[m][k]*B[n][k]  (row-major MxK / NxK, bf16 in)
// 128x128 tile, BK=32, 256 threads (2x2 waves, each 64x64 via 4x4 16x16x32).
enum { EP_F32_SCALE = 0, EP_TRI_WRITE = 1, EP_TRI_ADD = 2, EP_BF16 = 3,
       EP_BF16_BIAS = 4, EP_SIG = 5, EP_F32_BIAS = 6 };

template<int EP, bool CQK, bool CKV>
__global__ __launch_bounds__(256) void gemm_nt(
    const unsigned short* __restrict__ A, int lda, long sAz,
    const unsigned short* __restrict__ B, int ldb, long sBz,
    void* Cv, int ldc, long sCz,
    int K, float scale, const float* __restrict__ bias, int rowoff)
{
  const int mt = blockIdx.x, nt = blockIdx.y, z = blockIdx.z;
  if (CQK && nt > mt) return;  // causal: tile fully above diagonal
  __shared__ unsigned short As[4096];  // 128 x 32 bf16
  __shared__ unsigned short Bs[4096];
  const int tid = threadIdx.x;
  const int w = tid >> 6, lane = tid & 63;
  const int wm = w >> 1, wn = w & 1;
  const int lr = lane & 15, lk = lane >> 4;

  const unsigned short* Ab = A + (long)z * sAz + (long)mt * 128 * lda;
  const unsigned short* Bb = B + (long)z * sBz + (long)nt * 128 * ldb;

  f32x4 acc[4][4];
  #pragma unroll
  for (int i = 0; i < 4; i++)
    #pragma unroll
    for (int j = 0; j < 4; j++)
      acc[i][j] = (f32x4){0.f, 0.f, 0.f, 0.f};

  int Keff = K;
  if (CKV) { int kl = (mt + 1) * 128; if (kl < Keff) Keff = kl; }
  const int nkt = Keff >> 5;

  for (int kt = 0; kt < nkt; ++kt) {
    #pragma unroll
    for (int i = 0; i < 2; i++) {
      const int c = tid + i * 256;
      const unsigned short* ga = Ab + (long)(c >> 2) * lda + kt * 32 + (c & 3) * 8;
      const unsigned short* gb = Bb + (long)(c >> 2) * ldb + kt * 32 + (c & 3) * 8;
      __builtin_amdgcn_global_load_lds((__attribute__((address_space(1))) void*)(void*)ga,
                                       (__attribute__((address_space(3))) void*)(As + c * 8), 16, 0, 0);
      __builtin_amdgcn_global_load_lds((__attribute__((address_space(1))) void*)(void*)gb,
                                       (__attribute__((address_space(3))) void*)(Bs + c * 8), 16, 0, 0);
    }
    __syncthreads();
    bf16x8 af[4], bfr[4];
    #pragma unroll
    for (int i = 0; i < 4; i++) {
      u16x8 ua = *(const u16x8*)&As[(wm * 64 + i * 16 + lr) * 32 + lk * 8];
      u16x8 ub = *(const u16x8*)&Bs[(wn * 64 + i * 16 + lr) * 32 + lk * 8];
      af[i] = __builtin_bit_cast(bf16x8, ua);
      bfr[i] = __builtin_bit_cast(bf16x8, ub);
    }
    #pragma unroll
    for (int i = 0; i < 4; i++)
      #pragma unroll
      for (int j = 0; j < 4; j++)
        acc[i][j] = __builtin_amdgcn_mfma_f32_16x16x32_bf16(af[i], bfr[j], acc[i][j], 0, 0, 0);
    __syncthreads();
  }

  // D layout: row=(lane>>4)*4+reg, col=lane&15 (m89-verified)
  const long zo = (long)z * sCz;
  const int r0 = mt * 128 + wm * 64;
  const int c0 = nt * 128 + wn * 64;
  #pragma unroll
  for (int i = 0; i < 4; i++)
    #pragma unroll
    for (int j = 0; j < 4; j++)
      #pragma unroll
      for (int r = 0; r < 4; r++) {
        const int row = r0 + i * 16 + lk * 4 + r;
        const int col = c0 + j * 16 + lr;
        const float v = acc[i][j][r];
        const long idx = zo + (long)row * ldc + col;
        if constexpr (EP == EP_F32_SCALE) {
          ((float*)Cv)[idx] = v * scale;
        } else if constexpr (EP == EP_TRI_WRITE || EP == EP_TRI_ADD) {
          const float inv2047 = 1.f / 2047.f;
          const int gs = rowoff + row, m = gs >> 10, rr = gs & 1023;
          float wsum = 0.f;
          if (m >= 1) wsum += 0.5f + (float)(rr + 1024) * inv2047;
          if (m <= 6) wsum += 0.5f + (float)rr * inv2047;
          const float wgt = (0.5f + (float)row * inv2047) / (wsum + 1e-6f);
          if constexpr (EP == EP_TRI_WRITE) ((float*)Cv)[idx] = v * wgt;
          else                               ((float*)Cv)[idx] += v * wgt;
        } else if constexpr (EP == EP_BF16) {
          ((unsigned short*)Cv)[idx] = f2bf(v);
        } else if constexpr (EP == EP_BF16_BIAS) {
          ((unsigned short*)Cv)[idx] = f2bf(v + bias[col]);
        } else if constexpr (EP == EP_SIG) {
          const float g = v + bias[col];
          ((unsigned short*)Cv)[idx] = f2bf(1.f / (1.f + __expf(-g)));
        } else {
          ((float*)Cv)[idx] = v + bias[col];
        }
      }
}

// ------------------------------------------------------------- prep kernels
__global__ __launch_bounds__(256) void cast_bf_k(const float* __restrict__ in, unsigned short* __restrict__ out, long n) {
  long i = ((long)blockIdx.x * 256 + threadIdx.x) * 4;
  if (i >= n) return;
  f4 v = *(const f4*)&in[i];
  u16x4 o;
  #pragma unroll
  for (int j = 0; j < 4; j++) o[j] = f2bf(v[j]);
  *(u16x4*)&out[i] = o;
}

// Wc (o,d,k) -> W2[o][k*1024+d] bf16
__global__ __launch_bounds__(256) void wc2_k(const float* __restrict__ Wc, unsigned short* __restrict__ W2) {
  long i = (long)blockIdx.x * 256 + threadIdx.x;  // < 4,194,304
  int o = (int)(i >> 12), rem = (int)(i & 4095), k2 = rem >> 10, d = rem & 1023;
  W2[i] = f2bf(Wc[((long)o << 12) + (d << 2) + k2]);
}

// gm -> gt rows 128..255 (both batches)
__global__ __launch_bounds__(256) void gmfill_k(const float* __restrict__ gm, unsigned short* __restrict__ gt) {
  long i = (long)blockIdx.x * 256 + threadIdx.x;  // < 262,144
  int d = (int)(i & 1023), g = (int)((i >> 10) & 127), b = (int)(i >> 17);
  gt[((long)b * 256 + 128 + g) * 1024 + d] = f2bf(gm[(long)g * 1024 + d]);
}

// x (b,s,d) f32 -> xT (b,d,s) bf16
__global__ __launch_bounds__(256) void transp_xT_k(const float* __restrict__ x, unsigned short* __restrict__ xT) {
  __shared__ unsigned short tl[32][33];
  const int s0 = blockIdx.x * 32, d0 = blockIdx.y * 32;
  const long b = blockIdx.z;
  const int tx = threadIdx.x & 31, ty = threadIdx.x >> 5;
  const float* xb = x + b * 8388608;
  unsigned short* xtb = xT + b * 8388608;
  #pragma unroll
  for (int k = 0; k < 4; k++) tl[ty + k * 8][tx] = f2bf(xb[(long)(s0 + ty + k * 8) * 1024 + d0 + tx]);
  __syncthreads();
  #pragma unroll
  for (int k = 0; k < 4; k++) xtb[(long)(d0 + ty + k * 8) * 8192 + s0 + tx] = tl[tx][ty + k * 8];
}

// gt (b,256,1024) -> gtT (b,1024,256)
__global__ __launch_bounds__(256) void transp_gt_k(const unsigned short* __restrict__ gt, unsigned short* __restrict__ gtT) {
  __shared__ unsigned short tl[32][33];
  const int r0 = blockIdx.x * 32, c0 = blockIdx.y * 32;
  const long b = blockIdx.z;
  const int tx = threadIdx.x & 31, ty = threadIdx.x >> 5;
  const unsigned short* in = gt + b * 262144;
  unsigned short* out = gtT + b * 262144;
  #pragma unroll
  for (int k = 0; k < 4; k++) tl[ty + k * 8][tx] = in[(long)(r0 + ty + k * 8) * 1024 + c0 + tx];
  __syncthreads();
  #pragma unroll
  for (int k = 0; k < 4; k++) out[(long)(c0 + ty + k * 8) * 256 + r0 + tx] = tl[tx][ty + k * 8];
}

// ------------------------------------------------------------- softmaxes
// SWA: one (batch,window) at a time; row q of 2048; causal; no max-sub (f32 safe)
__global__ __launch_bounds__(256) void smax_swa_k(const float* __restrict__ S, unsigned short* __restrict__ P) {
  const int q = blockIdx.x, t = threadIdx.x;
  const float* row = S + (long)q * 2048;
  unsigned short* prow = P + (long)q * 2048;
  float e0[4], e1[4];
  float lsum = 0.f;
  const int k0 = t * 4, k1 = 1024 + t * 4;
  f4 v0 = *(const f4*)&row[k0];
  f4 v1 = *(const f4*)&row[k1];
  #pragma unroll
  for (int j = 0; j < 4; j++) { float e = (k0 + j <= q) ? __expf(v0[j]) : 0.f; e0[j] = e; lsum += e; }
  #pragma unroll
  for (int j = 0; j < 4; j++) { float e = (k1 + j <= q) ? __expf(v1[j]) : 0.f; e1[j] = e; lsum += e; }
  const float inv = 1.f / block_sum_256(lsum);
  u16x4 o0, o1;
  #pragma unroll
  for (int j = 0; j < 4; j++) { o0[j] = f2bf(e0[j] * inv); o1[j] = f2bf(e1[j] * inv); }
  *(u16x4*)&prow[k0] = o0;
  *(u16x4*)&prow[k1] = o1;
}

// global attn softmax: rows of 256
__global__ __launch_bounds__(256) void smax_g_k(const float* __restrict__ L, unsigned short* __restrict__ Pg) {
  const long row = blockIdx.x + (long)blockIdx.y * 8192;
  const int t = threadIdx.x;
  const float e = __expf(L[row * 256 + t]);
  const float tot = block_sum_256(e);
  Pg[row * 256 + t] = f2bf(e / tot);
}

// ------------------------------------------------------------- local cast
// evenb holds fully-combined, normalized local output (f32) -> cat[:, :, 0:1024)
__global__ __launch_bounds__(256) void cast_local_k(const float* __restrict__ ev, unsigned short* __restrict__ cat) {
  const long i = (long)blockIdx.x * 256 + threadIdx.x;  // < 4,194,304 (4-d groups)
  const int d4 = (int)(i & 255);
  const long bs = i >> 8;
  f4 e = *(const f4*)&ev[bs * 1024 + d4 * 4];
  u16x4 ov;
  #pragma unroll
  for (int j = 0; j < 4; j++) ov[j] = f2bf(e[j]);
  *(u16x4*)&cat[bs * 2048 + d4 * 4] = ov;
}

// ------------------------------------------------------------- broadcast
// strides 1..128 in an LDS tile: 1024 central rows + 255 halo, 16 d-cols.
__global__ __launch_bounds__(512) void bcast_small_k(const float* __restrict__ x, float* __restrict__ x8,
                                                     float* __restrict__ rp) {
  __shared__ float xs[1534 * 16];
  const int s0 = blockIdx.x << 10, d0 = blockIdx.y << 4;
  const long bb = (long)blockIdx.z * 8388608;
  const int t = threadIdx.x;
  #pragma unroll
  for (int i = 0; i < 12; i++) {
    const int g = t + i * 512;
    if (g < 1534 * 4) {
      const int row = g >> 2, dq = (g & 3) * 4;
      const int s = (s0 - 255 + row) & 8191;
      *(f4*)&xs[row * 16 + dq] = *(const f4*)&x[bb + ((long)s << 10) + d0 + dq];
    }
  }
  __syncthreads();
  f4 res[8];
  #pragma unroll
  for (int i = 0; i < 8; i++) res[i] = (f4){0.f, 0.f, 0.f, 0.f};
  #pragma unroll
  for (int it = 0; it < 8; ++it) {
    const int st = 1 << it;
    const int lo = (st << 1) - 1;
    const int ngr = (1534 - 2 * lo) * 4;
    f4 tmp[12];
    #pragma unroll
    for (int i = 0; i < 12; i++) {
      const int g = t + i * 512;
      if (g < ngr) {
        const int row = lo + (g >> 2), dq = (g & 3) * 4;
        f4 c = *(f4*)&xs[row * 16 + dq];
        f4 up = *(f4*)&xs[(row - st) * 16 + dq];
        f4 dn = *(f4*)&xs[(row + st) * 16 + dq];
        tmp[i] = c + 0.5f * (up + dn);
      }
    }
    __syncthreads();
    #pragma unroll
    for (int i = 0; i < 12; i++) {
      const int g = t + i * 512;
      if (g < ngr) { const int row = lo + (g >> 2), dq = (g & 3) * 4; *(f4*)&xs[row * 16 + dq] = tmp[i]; }
    }
    __syncthreads();
    #pragma unroll
    for (int i = 0; i < 8; i++) {
      const int cg = t + i * 512;
      const int row = 255 + (cg >> 2), dq = (cg & 3) * 4;
      res[i] += *(f4*)&xs[row * 16 + dq];
    }
  }
  #pragma unroll
  for (int i = 0; i < 8; i++) {
    const int cg = t + i * 512;
    const int row = cg >> 2, dq = (cg & 3) * 4;
    const long off = bb + ((long)(s0 + row) << 10) + d0 + dq;
    *(f4*)&x8[off] = *(f4*)&xs[(255 + row) * 16 + dq];
    *(f4*)&rp[off] = res[i];
  }
}

// strides 256..4096 on closed 32-groups {s = r mod 256}; writes out in-place on rp.
__global__ __launch_bounds__(256) void bcast_big_k(const float* __restrict__ x8, float* __restrict__ rp) {
  const long tid = (long)blockIdx.x * 256 + threadIdx.x;  // < 524,288
  const int d = (int)(tid & 1023), r = (int)((tid >> 10) & 255), b = (int)(tid >> 18);
  const long base = ((long)b << 23) + ((long)r << 10) + d;
  float v[32], rs[32];
  #pragma unroll
  for (int j = 0; j < 32; j++) v[j] = x8[base + ((long)j << 18)];
  #pragma unroll
  for (int j = 0; j < 32; j++) rs[j] = rp[base + ((long)j << 18)];
#define BSTEP(u) { float nv[32]; \
  _Pragma("unroll") for (int j = 0; j < 32; j++) nv[j] = v[j] + 0.5f * (v[(j - (u)) & 31] + v[(j + (u)) & 31]); \
  _Pragma("unroll") for (int j = 0; j < 32; j++) { v[j] = nv[j]; rs[j] += nv[j]; } }
  BSTEP(1) BSTEP(2) BSTEP(4) BSTEP(8) BSTEP(16)
#undef BSTEP
  const float sc = 1.f / 14.f;  // log2(8192)+1
  #pragma unroll
  for (int j = 0; j < 32; j++) rp[base + ((long)j << 18)] = rs[j] * sc;
}

// ------------------------------------------------------------- final mix
__global__ __launch_bounds__(256) void mixed_k(const unsigned short* __restrict__ mw, const unsigned short* __restrict__ cat,
                                               const float* __restrict__ bc_, unsigned short* __restrict__ mx) {
  const long i = (long)blockIdx.x * 256 + threadIdx.x;  // < 4,194,304
  const int d4 = (int)(i & 255);
  const long bs = i >> 8;
  const long off1 = bs * 1024 + d4 * 4;
  const long off2 = bs * 2048 + d4 * 4;
  u16x4 mwv = *(const u16x4*)&mw[off1];
  u16x4 lv = *(const u16x4*)&cat[off2];
  u16x4 gv = *(const u16x4*)&cat[off2 + 1024];
  f4 bcv = *(const f4*)&bc_[off1];
  u16x4 o;
  #pragma unroll
  for (int j = 0; j < 4; j++) {
    const float m = bf2f(mwv[j]);
    o[j] = f2bf(m * bf2f(lv[j]) + (1.f - m) * bf2f(gv[j]) + bcv[j]);
  }
  *(u16x4*)&mx[off1] = o;
}

// ------------------------------------------------------------- launcher
extern "C" void kernel_launch(void* const* d_in, const int* in_sizes, int n_in,
                              void* d_out, int out_size, void* d_ws, size_t ws_size,
                              hipStream_t stream) {
  (void)in_sizes; (void)n_in; (void)out_size;
  if (ws_size < (size_t)251658240) return;  // diagnostic: fail clean, not fault
  const float* x  = (const float*)d_in[0];
  const float* gm = (const float*)d_in[1];
  const float* Wc = (const float*)d_in[2];
  const float* bc = (const float*)d_in[3];
  const float* Wm = (const float*)d_in[4];
  const float* bm = (const float*)d_in[5];
  const float* Wo = (const float*)d_in[6];
  const float* bo = (const float*)d_in[7];
  char* ws = (char*)d_ws;

  // layout (byte offsets), total 240 MB:
  unsigned short* xbf  = (unsigned short*)(ws + 0);          // 32 MB bf16 x
  unsigned short* xbfT = (unsigned short*)(ws + 33554432);   // 32 MB bf16 xT
  float*          S1   = (float*)(ws + 67108864);            // 16 MB scores/logits
  unsigned short* P1   = (unsigned short*)(ws + 83886080);   // 8 MB P / Pg
  unsigned short* mwb  = (unsigned short*)(ws + 67108864);   // 32 MB (reuse S1/P1 region)
  float*          evenb= (float*)(ws + 100663296);           // 64 MB f32 acc / x8
  unsigned short* mxb  = (unsigned short*)(ws + 100663296);  // 32 MB (reuse evenb)
  unsigned short* cat  = (unsigned short*)(ws + 167772160);  // 64 MB [local|glob]
  unsigned short* gt   = (unsigned short*)(ws + 234881024);  // 1 MB
  unsigned short* gtT  = (unsigned short*)(ws + 235929600);  // 1 MB
  unsigned short* wc2  = (unsigned short*)(ws + 236978176);  // 8 MB
  unsigned short* wmb  = (unsigned short*)(ws + 245366784);  // 4 MB
  unsigned short* wob  = (unsigned short*)(ws + 249561088);  // 2 MB
  float*          rp   = (float*)(ws + 0);                   // 64 MB (over xbf+xbfT)
  float*          x8   = evenb;

  // A. casts / permutes
  cast_bf_k<<<16384, 256, 0, stream>>>(x, xbf, 16777216L);
  cast_bf_k<<<2048, 256, 0, stream>>>(Wm, wmb, 2097152L);
  cast_bf_k<<<1024, 256, 0, stream>>>(Wo, wob, 1048576L);
  wc2_k<<<16384, 256, 0, stream>>>(Wc, wc2);
  gmfill_k<<<1024, 256, 0, stream>>>(gm, gt);
  transp_xT_k<<<dim3(256, 32, 2), 256, 0, stream>>>(x, xbfT);

  // B. compressed global attention
  gemm_nt<EP_BF16_BIAS, false, false><<<dim3(1, 8, 2), 256, 0, stream>>>(
      xbf, 4096, 8388608L, wc2, 4096, 0L, gt, 1024, 262144L, 4096, 1.f, bc, 0);
  transp_gt_k<<<dim3(8, 32, 2), 256, 0, stream>>>(gt, gtT);
  gemm_nt<EP_F32_SCALE, false, false><<<dim3(64, 2, 2), 256, 0, stream>>>(
      xbf, 1024, 8388608L, gt, 1024, 262144L, S1, 256, 2097152L, 1024, 0.03125f, nullptr, 0);
  smax_g_k<<<dim3(8192, 2), 256, 0, stream>>>(S1, P1);
  gemm_nt<EP_BF16, false, false><<<dim3(64, 8, 2), 256, 0, stream>>>(
      P1, 256, 2097152L, gtT, 256, 262144L, cat + 1024, 2048, 16777216L, 256, 1.f, nullptr, 0);

  // C. sliding-window attention, window n covers rows [n*1024, n*1024+2048)
  //    even windows (0,2,4,6) tile [0,8192) disjointly -> write;
  //    odd windows (1,3,5) -> accumulate.  Weight tri(r)/wsum(s) in epilogue.
  for (int z = 0; z < 2; z++) {
    const long xo = (long)z * 8388608;
    for (int n = 0; n < 7; n += 2) {  // even first (writes)
      gemm_nt<EP_F32_SCALE, true, false><<<dim3(16, 16, 1), 256, 0, stream>>>(
          xbf + xo + (long)n * 1048576, 1024, 0L,
          xbf + xo + (long)n * 1048576, 1024, 0L,
          S1, 2048, 0L, 1024, 0.03125f, nullptr, 0);
      smax_swa_k<<<2048, 256, 0, stream>>>(S1, P1);
      gemm_nt<EP_TRI_WRITE, false, true><<<dim3(16, 8, 1), 256, 0, stream>>>(
          P1, 2048, 0L, xbfT + xo + (long)n * 1024, 8192, 0L,
          evenb + xo + (long)n * 1048576, 1024, 0L, 2048, 1.f, nullptr, n * 1024);
    }
    for (int n = 1; n < 7; n += 2) {  // odd (accumulate)
      gemm_nt<EP_F32_SCALE, true, false><<<dim3(16, 16, 1), 256, 0, stream>>>(
          xbf + xo + (long)n * 1048576, 1024, 0L,
          xbf + xo + (long)n * 1048576, 1024, 0L,
          S1, 2048, 0L, 1024, 0.03125f, nullptr, 0);
      smax_swa_k<<<2048, 256, 0, stream>>>(S1, P1);
      gemm_nt<EP_TRI_ADD, false, true><<<dim3(16, 8, 1), 256, 0, stream>>>(
          P1, 2048, 0L, xbfT + xo + (long)n * 1024, 8192, 0L,
          evenb + xo + (long)n * 1048576, 1024, 0L, 2048, 1.f, nullptr, n * 1024);
    }
  }
  cast_local_k<<<16384, 256, 0, stream>>>(evenb, cat);

  // D. gate gemm (cat complete; S1/P1 dead -> mwb reuses their region)
  gemm_nt<EP_SIG, false, false><<<dim3(128, 8, 1), 256, 0, stream>>>(
      cat, 2048, 0L, wmb, 2048, 0L, mwb, 1024, 0L, 2048, 1.f, bm, 0);

  // E. information broadcast (reads original f32 x; rp over dead xbf/xbfT)
  bcast_small_k<<<dim3(8, 64, 2), 512, 0, stream>>>(x, x8, rp);
  bcast_big_k<<<2048, 256, 0, stream>>>(x8, rp);

  // F. mix + output projection
  mixed_k<<<16384, 256, 0, stream>>>(mwb, cat, rp, mxb);
  gemm_nt<EP_F32_BIAS, false, false><<<dim3(128, 8, 1), 256, 0, stream>>>(
      mxb, 1024, 0L, wob, 1024, 0L, (float*)d_out, 1024, 0L, 1024, 1.f, bo, 0);
}

// Round 5
// 1749.466 us; speedup vs baseline: 1.1127x; 1.1127x over previous
//
#include <hip/hip_runtime.h>

// HybridStateSpaceAttention on MI355X (gfx950).  Workspace: exactly 240 MB.
// r4 (resubmit after infra timeout): bcast in transposed domain (in-place
// column stencil), comp gemm split-K x8, SWA PV writes bf16 direct to cat.
//
// ws layout (M = 1 MiB):
//   @0    xbf  32M (bf16 x)         -> later mxb
//   @32M  xbfT 32M (bf16 x^T)       -> later mwb
//   @64M  xTf  64M (f32 x^T)        -> in-place becomes bcast result rpT
//   @128M cat  64M (bf16 [local|glob])
//   @192M S1   16M (f32 scores / logits)
//   @208M P1    8M (bf16 P / Pg)
//   @216M gt 1M | @217M gtT 1M | @218M wc2 8M | @226M wmb 4M | @230M wob 2M
//   @232M parts 8M (f32 split-K partials)

#define DEV __device__ __forceinline__

typedef float f4 __attribute__((ext_vector_type(4)));
typedef float f32x4 __attribute__((ext_vector_type(4)));
typedef unsigned short u16x4 __attribute__((ext_vector_type(4)));
typedef unsigned short u16x8 __attribute__((ext_vector_type(8)));
typedef __bf16 bf16x8 __attribute__((ext_vector_type(8)));

DEV unsigned short f2bf(float f) {
  unsigned u = __float_as_uint(f);
  return (unsigned short)((u + 0x7FFFu + ((u >> 16) & 1u)) >> 16);
}
DEV float bf2f(unsigned short h) { return __uint_as_float(((unsigned)h) << 16); }

DEV float block_sum_256(float v) {
  #pragma unroll
  for (int o = 32; o > 0; o >>= 1) v += __shfl_down(v, o, 64);
  __shared__ float sw[4];
  if ((threadIdx.x & 63) == 0) sw[threadIdx.x >> 6] = v;
  __syncthreads();
  return sw[0] + sw[1] + sw[2] + sw[3];
}

// ---------------------------------------------------------------- GEMM (NT)
// C[m][n] = sum_k A[m][k]*B[n][k]  (row-major MxK / NxK, bf16 in)
// 128x128 tile, BK=32, 256 threads (2x2 waves, each 64x64 via 4x4 16x16x32).
// SPLITK: blockIdx.z encodes (kc = z>>1, b = z&1); K = chunk length.
enum { EP_F32_SCALE = 0, EP_TRI_WRITE = 1, EP_TRI_ADD = 2, EP_BF16 = 3,
       EP_BF16_BIAS = 4, EP_SIG = 5, EP_F32_BIAS = 6, EP_F32_PART = 7 };

template<int EP, bool CQK, bool CKV, bool SPLITK>
__global__ __launch_bounds__(256) void gemm_nt(
    const unsigned short* __restrict__ A, int lda, long sAz,
    const unsigned short* __restrict__ B, int ldb, long sBz,
    void* Cv, int ldc, long sCz,
    int K, float scale, const float* __restrict__ bias, int rowoff)
{
  const int mt = blockIdx.x, nt = blockIdx.y, z = blockIdx.z;
  if (CQK && nt > mt) return;  // causal: tile fully above diagonal
  __shared__ unsigned short As[4096];  // 128 x 32 bf16
  __shared__ unsigned short Bs[4096];
  const int tid = threadIdx.x;
  const int w = tid >> 6, lane = tid & 63;
  const int wm = w >> 1, wn = w & 1;
  const int lr = lane & 15, lk = lane >> 4;

  int zb = z, koff = 0;
  if (SPLITK) { zb = z & 1; koff = (z >> 1) * K; }

  const unsigned short* Ab = A + (long)zb * sAz + (long)mt * 128 * lda + koff;
  const unsigned short* Bb = B + (long)zb * sBz + (long)nt * 128 * ldb + koff;

  f32x4 acc[4][4];
  #pragma unroll
  for (int i = 0; i < 4; i++)
    #pragma unroll
    for (int j = 0; j < 4; j++)
      acc[i][j] = (f32x4){0.f, 0.f, 0.f, 0.f};

  int Keff = K;
  if (CKV) { int kl = (mt + 1) * 128; if (kl < Keff) Keff = kl; }
  const int nkt = Keff >> 5;

  for (int kt = 0; kt < nkt; ++kt) {
    #pragma unroll
    for (int i = 0; i < 2; i++) {
      const int c = tid + i * 256;
      const unsigned short* ga = Ab + (long)(c >> 2) * lda + kt * 32 + (c & 3) * 8;
      const unsigned short* gb = Bb + (long)(c >> 2) * ldb + kt * 32 + (c & 3) * 8;
      __builtin_amdgcn_global_load_lds((__attribute__((address_space(1))) void*)(void*)ga,
                                       (__attribute__((address_space(3))) void*)(As + c * 8), 16, 0, 0);
      __builtin_amdgcn_global_load_lds((__attribute__((address_space(1))) void*)(void*)gb,
                                       (__attribute__((address_space(3))) void*)(Bs + c * 8), 16, 0, 0);
    }
    __syncthreads();
    bf16x8 af[4], bfr[4];
    #pragma unroll
    for (int i = 0; i < 4; i++) {
      u16x8 ua = *(const u16x8*)&As[(wm * 64 + i * 16 + lr) * 32 + lk * 8];
      u16x8 ub = *(const u16x8*)&Bs[(wn * 64 + i * 16 + lr) * 32 + lk * 8];
      af[i] = __builtin_bit_cast(bf16x8, ua);
      bfr[i] = __builtin_bit_cast(bf16x8, ub);
    }
    #pragma unroll
    for (int i = 0; i < 4; i++)
      #pragma unroll
      for (int j = 0; j < 4; j++)
        acc[i][j] = __builtin_amdgcn_mfma_f32_16x16x32_bf16(af[i], bfr[j], acc[i][j], 0, 0, 0);
    __syncthreads();
  }

  // D layout: row=(lane>>4)*4+reg, col=lane&15 (m89-verified)
  const long zo = (long)z * sCz;
  const int r0 = mt * 128 + wm * 64;
  const int c0 = nt * 128 + wn * 64;
  #pragma unroll
  for (int i = 0; i < 4; i++)
    #pragma unroll
    for (int j = 0; j < 4; j++)
      #pragma unroll
      for (int r = 0; r < 4; r++) {
        const int row = r0 + i * 16 + lk * 4 + r;
        const int col = c0 + j * 16 + lr;
        const float v = acc[i][j][r];
        const long idx = zo + (long)row * ldc + col;
        if constexpr (EP == EP_F32_SCALE) {
          ((float*)Cv)[idx] = v * scale;
        } else if constexpr (EP == EP_TRI_WRITE || EP == EP_TRI_ADD) {
          const float inv2047 = 1.f / 2047.f;
          const int gs = rowoff + row, m = gs >> 10, rr = gs & 1023;
          float wsum = 0.f;
          if (m >= 1) wsum += 0.5f + (float)(rr + 1024) * inv2047;
          if (m <= 6) wsum += 0.5f + (float)rr * inv2047;
          const float wgt = (0.5f + (float)row * inv2047) / (wsum + 1e-6f);
          unsigned short* cp = (unsigned short*)Cv;
          if constexpr (EP == EP_TRI_WRITE) cp[idx] = f2bf(v * wgt);
          else                               cp[idx] = f2bf(bf2f(cp[idx]) + v * wgt);
        } else if constexpr (EP == EP_BF16) {
          ((unsigned short*)Cv)[idx] = f2bf(v);
        } else if constexpr (EP == EP_BF16_BIAS) {
          ((unsigned short*)Cv)[idx] = f2bf(v + bias[col]);
        } else if constexpr (EP == EP_SIG) {
          const float g = v + bias[col];
          ((unsigned short*)Cv)[idx] = f2bf(1.f / (1.f + __expf(-g)));
        } else if constexpr (EP == EP_F32_PART) {
          ((float*)Cv)[idx] = v;
        } else {
          ((float*)Cv)[idx] = v + bias[col];
        }
      }
}

// ------------------------------------------------------------- prep kernels
__global__ __launch_bounds__(256) void cast_bf_k(const float* __restrict__ in, unsigned short* __restrict__ out, long n) {
  long i = ((long)blockIdx.x * 256 + threadIdx.x) * 4;
  if (i >= n) return;
  f4 v = *(const f4*)&in[i];
  u16x4 o;
  #pragma unroll
  for (int j = 0; j < 4; j++) o[j] = f2bf(v[j]);
  *(u16x4*)&out[i] = o;
}

// Wc (o,d,k) -> W2[o][k*1024+d] bf16
__global__ __launch_bounds__(256) void wc2_k(const float* __restrict__ Wc, unsigned short* __restrict__ W2) {
  long i = (long)blockIdx.x * 256 + threadIdx.x;  // < 4,194,304
  int o = (int)(i >> 12), rem = (int)(i & 4095), k2 = rem >> 10, d = rem & 1023;
  W2[i] = f2bf(Wc[((long)o << 12) + (d << 2) + k2]);
}

// gm -> gt rows 128..255 (both batches)
__global__ __launch_bounds__(256) void gmfill_k(const float* __restrict__ gm, unsigned short* __restrict__ gt) {
  long i = (long)blockIdx.x * 256 + threadIdx.x;  // < 262,144
  int d = (int)(i & 1023), g = (int)((i >> 10) & 127), b = (int)(i >> 17);
  gt[((long)b * 256 + 128 + g) * 1024 + d] = f2bf(gm[(long)g * 1024 + d]);
}

// x (b,s,d) f32 -> xbfT (b,d,s) bf16 AND xTf (b,d,s) f32
__global__ __launch_bounds__(256) void transp_x3_k(const float* __restrict__ x, unsigned short* __restrict__ xT,
                                                   float* __restrict__ xTf) {
  __shared__ float tlf[32][33];
  const int s0 = blockIdx.x * 32, d0 = blockIdx.y * 32;
  const long b = blockIdx.z;
  const int tx = threadIdx.x & 31, ty = threadIdx.x >> 5;
  const float* xb = x + b * 8388608;
  unsigned short* xtb = xT + b * 8388608;
  float* xtf = xTf + b * 8388608;
  #pragma unroll
  for (int k = 0; k < 4; k++) tlf[ty + k * 8][tx] = xb[(long)(s0 + ty + k * 8) * 1024 + d0 + tx];
  __syncthreads();
  #pragma unroll
  for (int k = 0; k < 4; k++) {
    const float val = tlf[tx][ty + k * 8];
    const long o = (long)(d0 + ty + k * 8) * 8192 + s0 + tx;
    xtb[o] = f2bf(val);
    xtf[o] = val;
  }
}

// gt (b,256,1024) -> gtT (b,1024,256)
__global__ __launch_bounds__(256) void transp_gt_k(const unsigned short* __restrict__ gt, unsigned short* __restrict__ gtT) {
  __shared__ unsigned short tl[32][33];
  const int r0 = blockIdx.x * 32, c0 = blockIdx.y * 32;
  const long b = blockIdx.z;
  const int tx = threadIdx.x & 31, ty = threadIdx.x >> 5;
  const unsigned short* in = gt + b * 262144;
  unsigned short* out = gtT + b * 262144;
  #pragma unroll
  for (int k = 0; k < 4; k++) tl[ty + k * 8][tx] = in[(long)(r0 + ty + k * 8) * 1024 + c0 + tx];
  __syncthreads();
  #pragma unroll
  for (int k = 0; k < 4; k++) out[(long)(c0 + ty + k * 8) * 256 + r0 + tx] = tl[tx][ty + k * 8];
}

// ------------------------------------------------------------- softmaxes
// SWA: one (batch,window); row q of 2048; causal; no max-sub (f32 safe)
__global__ __launch_bounds__(256) void smax_swa_k(const float* __restrict__ S, unsigned short* __restrict__ P) {
  const int q = blockIdx.x, t = threadIdx.x;
  const float* row = S + (long)q * 2048;
  unsigned short* prow = P + (long)q * 2048;
  float e0[4], e1[4];
  float lsum = 0.f;
  const int k0 = t * 4, k1 = 1024 + t * 4;
  f4 v0 = *(const f4*)&row[k0];
  f4 v1 = *(const f4*)&row[k1];
  #pragma unroll
  for (int j = 0; j < 4; j++) { float e = (k0 + j <= q) ? __expf(v0[j]) : 0.f; e0[j] = e; lsum += e; }
  #pragma unroll
  for (int j = 0; j < 4; j++) { float e = (k1 + j <= q) ? __expf(v1[j]) : 0.f; e1[j] = e; lsum += e; }
  const float inv = 1.f / block_sum_256(lsum);
  u16x4 o0, o1;
  #pragma unroll
  for (int j = 0; j < 4; j++) { o0[j] = f2bf(e0[j] * inv); o1[j] = f2bf(e1[j] * inv); }
  *(u16x4*)&prow[k0] = o0;
  *(u16x4*)&prow[k1] = o1;
}

// global attn softmax: rows of 256
__global__ __launch_bounds__(256) void smax_g_k(const float* __restrict__ L, unsigned short* __restrict__ Pg) {
  const long row = blockIdx.x + (long)blockIdx.y * 8192;
  const int t = threadIdx.x;
  const float e = __expf(L[row * 256 + t]);
  const float tot = block_sum_256(e);
  Pg[row * 256 + t] = f2bf(e / tot);
}

// ------------------------------------------------------------- comp reduce
__global__ __launch_bounds__(256) void reduce_comp_k(const float* __restrict__ parts, const float* __restrict__ bc,
                                                     unsigned short* __restrict__ gt) {
  const int i = blockIdx.x * 256 + threadIdx.x;  // < 262144
  const int o = i & 1023, t = (i >> 10) & 127, b = i >> 17;
  float s = bc[o];
  #pragma unroll
  for (int kc = 0; kc < 8; kc++) s += parts[(long)(kc * 2 + b) * 131072 + t * 1024 + o];
  gt[((long)b * 256 + t) * 1024 + o] = f2bf(s);
}

// ------------------------------------------------------------- broadcast
// All 13 strides on one (b,d) column of 8192, in LDS, in-place on xTf.
__global__ __launch_bounds__(256) void bcast_col_k(float* __restrict__ col) {
  __shared__ float xs[8192];
  float* c = col + (long)blockIdx.x * 8192;
  const int t = threadIdx.x;
  float v[32], rs[32];
  #pragma unroll
  for (int j = 0; j < 32; j++) {
    v[j] = c[t + j * 256];
    xs[t + j * 256] = v[j];
    rs[j] = 0.f;
  }
  __syncthreads();
  for (int it = 0; it < 13; ++it) {
    const int st = 1 << it;
    float nv[32];
    #pragma unroll
    for (int j = 0; j < 32; j++) {
      const int e = t + j * 256;
      nv[j] = v[j] + 0.5f * (xs[(e - st) & 8191] + xs[(e + st) & 8191]);
    }
    __syncthreads();
    #pragma unroll
    for (int j = 0; j < 32; j++) {
      xs[t + j * 256] = nv[j];
      v[j] = nv[j];
      rs[j] += nv[j];
    }
    __syncthreads();
  }
  const float sc = 1.f / 14.f;  // log2(8192)+1
  #pragma unroll
  for (int j = 0; j < 32; j++) c[t + j * 256] = rs[j] * sc;
}

// ------------------------------------------------------------- final mix
// reads bcast result in transposed layout (b,d,s) via 32x32 LDS tile
__global__ __launch_bounds__(256) void mixed_t_k(const unsigned short* __restrict__ mw, const unsigned short* __restrict__ cat,
                                                 const float* __restrict__ rpT, unsigned short* __restrict__ mx) {
  __shared__ float tlf[32][36];
  const int s0 = blockIdx.x * 32, d0 = blockIdx.y * 32;
  const long b = blockIdx.z;
  const int t = threadIdx.x;
  const int tr = t >> 3, tc4 = (t & 7) * 4;
  *(f4*)&tlf[tr][tc4] = *(const f4*)&rpT[b * 8388608 + (long)(d0 + tr) * 8192 + s0 + tc4];
  __syncthreads();
  const long row = b * 8192 + s0 + tr;  // tr reused as s-row, tc4 as d-group
  u16x4 mwv = *(const u16x4*)&mw[row * 1024 + d0 + tc4];
  u16x4 lv  = *(const u16x4*)&cat[row * 2048 + d0 + tc4];
  u16x4 gv  = *(const u16x4*)&cat[row * 2048 + 1024 + d0 + tc4];
  u16x4 o;
  #pragma unroll
  for (int j = 0; j < 4; j++) {
    const float m = bf2f(mwv[j]);
    o[j] = f2bf(m * bf2f(lv[j]) + (1.f - m) * bf2f(gv[j]) + tlf[tc4 + j][tr]);
  }
  *(u16x4*)&mx[row * 1024 + d0 + tc4] = o;
}

// ------------------------------------------------------------- launcher
extern "C" void kernel_launch(void* const* d_in, const int* in_sizes, int n_in,
                              void* d_out, int out_size, void* d_ws, size_t ws_size,
                              hipStream_t stream) {
  (void)in_sizes; (void)n_in; (void)out_size;
  if (ws_size < (size_t)251658240) return;  // 240 MB gate: fail clean, not fault
  const float* x  = (const float*)d_in[0];
  const float* gm = (const float*)d_in[1];
  const float* Wc = (const float*)d_in[2];
  const float* bc = (const float*)d_in[3];
  const float* Wm = (const float*)d_in[4];
  const float* bm = (const float*)d_in[5];
  const float* Wo = (const float*)d_in[6];
  const float* bo = (const float*)d_in[7];
  char* ws = (char*)d_ws;
  const long M = 1048576;

  unsigned short* xbf  = (unsigned short*)(ws + 0 * M);    // 32 MB
  unsigned short* xbfT = (unsigned short*)(ws + 32 * M);   // 32 MB
  float*          xTf  = (float*)(ws + 64 * M);            // 64 MB (in-place -> rpT)
  unsigned short* cat  = (unsigned short*)(ws + 128 * M);  // 64 MB
  float*          S1   = (float*)(ws + 192 * M);           // 16 MB
  unsigned short* P1   = (unsigned short*)(ws + 208 * M);  // 8 MB
  unsigned short* gt   = (unsigned short*)(ws + 216 * M);  // 1 MB
  unsigned short* gtT  = (unsigned short*)(ws + 217 * M);  // 1 MB
  unsigned short* wc2  = (unsigned short*)(ws + 218 * M);  // 8 MB
  unsigned short* wmb  = (unsigned short*)(ws + 226 * M);  // 4 MB
  unsigned short* wob  = (unsigned short*)(ws + 230 * M);  // 2 MB
  float*          parts= (float*)(ws + 232 * M);           // 8 MB
  unsigned short* mwb  = (unsigned short*)(ws + 32 * M);   // reuse xbfT
  unsigned short* mxb  = (unsigned short*)(ws + 0 * M);    // reuse xbf
  float*          rpT  = xTf;

  // A. casts / permutes
  cast_bf_k<<<16384, 256, 0, stream>>>(x, xbf, 16777216L);
  cast_bf_k<<<2048, 256, 0, stream>>>(Wm, wmb, 2097152L);
  cast_bf_k<<<1024, 256, 0, stream>>>(Wo, wob, 1048576L);
  wc2_k<<<16384, 256, 0, stream>>>(Wc, wc2);
  gmfill_k<<<1024, 256, 0, stream>>>(gm, gt);
  transp_x3_k<<<dim3(256, 32, 2), 256, 0, stream>>>(x, xbfT, xTf);

  // B. information broadcast (in-place on xTf -> rpT)
  bcast_col_k<<<2048, 256, 0, stream>>>(xTf);

  // C. compressed global attention (comp via split-K x8)
  gemm_nt<EP_F32_PART, false, false, true><<<dim3(1, 8, 16), 256, 0, stream>>>(
      xbf, 4096, 8388608L, wc2, 4096, 0L, parts, 1024, 131072L, 512, 1.f, nullptr, 0);
  reduce_comp_k<<<1024, 256, 0, stream>>>(parts, bc, gt);
  transp_gt_k<<<dim3(8, 32, 2), 256, 0, stream>>>(gt, gtT);
  gemm_nt<EP_F32_SCALE, false, false, false><<<dim3(64, 2, 2), 256, 0, stream>>>(
      xbf, 1024, 8388608L, gt, 1024, 262144L, S1, 256, 2097152L, 1024, 0.03125f, nullptr, 0);
  smax_g_k<<<dim3(8192, 2), 256, 0, stream>>>(S1, P1);
  gemm_nt<EP_BF16, false, false, false><<<dim3(64, 8, 2), 256, 0, stream>>>(
      P1, 256, 2097152L, gtT, 256, 262144L, cat + 1024, 2048, 16777216L, 256, 1.f, nullptr, 0);

  // D. sliding-window attention; PV writes bf16 direct into cat local half.
  //    Even windows (0,2,4,6) tile [0,8192) -> TRI_WRITE; odd -> TRI_ADD.
  for (int z = 0; z < 2; z++) {
    const long xo = (long)z * 8388608;
    const long co = (long)z * 16777216;
    for (int n = 0; n < 7; n += 2) {
      gemm_nt<EP_F32_SCALE, true, false, false><<<dim3(16, 16, 1), 256, 0, stream>>>(
          xbf + xo + (long)n * 1048576, 1024, 0L,
          xbf + xo + (long)n * 1048576, 1024, 0L,
          S1, 2048, 0L, 1024, 0.03125f, nullptr, 0);
      smax_swa_k<<<2048, 256, 0, stream>>>(S1, P1);
      gemm_nt<EP_TRI_WRITE, false, true, false><<<dim3(16, 8, 1), 256, 0, stream>>>(
          P1, 2048, 0L, xbfT + xo + (long)n * 1024, 8192, 0L,
          cat + co + (long)n * 2097152, 2048, 0L, 2048, 1.f, nullptr, n * 1024);
    }
    for (int n = 1; n < 7; n += 2) {
      gemm_nt<EP_F32_SCALE, true, false, false><<<dim3(16, 16, 1), 256, 0, stream>>>(
          xbf + xo + (long)n * 1048576, 1024, 0L,
          xbf + xo + (long)n * 1048576, 1024, 0L,
          S1, 2048, 0L, 1024, 0.03125f, nullptr, 0);
      smax_swa_k<<<2048, 256, 0, stream>>>(S1, P1);
      gemm_nt<EP_TRI_ADD, false, true, false><<<dim3(16, 8, 1), 256, 0, stream>>>(
          P1, 2048, 0L, xbfT + xo + (long)n * 1024, 8192, 0L,
          cat + co + (long)n * 2097152, 2048, 0L, 2048, 1.f, nullptr, n * 1024);
    }
  }

  // E. gate gemm (xbfT dead -> mwb overlays it)
  gemm_nt<EP_SIG, false, false, false><<<dim3(128, 8, 1), 256, 0, stream>>>(
      cat, 2048, 0L, wmb, 2048, 0L, mwb, 1024, 0L, 2048, 1.f, bm, 0);

  // F. mix (reads transposed bcast) + output projection
  mixed_t_k<<<dim3(256, 32, 2), 256, 0, stream>>>(mwb, cat, rpT, mxb);
  gemm_nt<EP_F32_BIAS, false, false, false><<<dim3(128, 8, 1), 256, 0, stream>>>(
      mxb, 1024, 0L, wob, 1024, 0L, (float*)d_out, 1024, 0L, 1024, 1.f, bo, 0);
}

// Round 8
// 1101.863 us; speedup vs baseline: 1.7667x; 1.5877x over previous
//
#include <hip/hip_runtime.h>

// HybridStateSpaceAttention on MI355X (gfx950).  Workspace: exactly 240 MB.
// r6 (second resubmit after infra timeouts): SWA batched across windows x
// batches (WIN mode in gemm_nt) -> >=2 blocks/CU instead of 1; broadcast
// moved after SWA (xTf reuses dead S).
//
// ws layout (M = 1 MiB):
//   @0    xbf  32M (bf16 x)          -> later mxb
//   @32M  xbfT 32M (bf16 x^T)        -> later mwb
//   @64M  cat  64M (bf16 [local|glob])
//   @128M BIG 96M:
//         phase C: parts@128 logits@136 Pg@152
//         SWA:     S 4x16M @128..192, P 4x8M @192..224
//         phase F: xTf 64M @128..192 (in-place bcast -> rpT)
//   @224M wmb 4M | @228M wob 2M | @230M gt 1M | @231M gtT 1M | @232M wc2 8M

#define DEV __device__ __forceinline__

typedef float f4 __attribute__((ext_vector_type(4)));
typedef float f32x4 __attribute__((ext_vector_type(4)));
typedef unsigned short u16x4 __attribute__((ext_vector_type(4)));
typedef unsigned short u16x8 __attribute__((ext_vector_type(8)));
typedef __bf16 bf16x8 __attribute__((ext_vector_type(8)));

DEV unsigned short f2bf(float f) {
  unsigned u = __float_as_uint(f);
  return (unsigned short)((u + 0x7FFFu + ((u >> 16) & 1u)) >> 16);
}
DEV float bf2f(unsigned short h) { return __uint_as_float(((unsigned)h) << 16); }

DEV float block_sum_256(float v) {
  #pragma unroll
  for (int o = 32; o > 0; o >>= 1) v += __shfl_down(v, o, 64);
  __shared__ float sw[4];
  if ((threadIdx.x & 63) == 0) sw[threadIdx.x >> 6] = v;
  __syncthreads();
  return sw[0] + sw[1] + sw[2] + sw[3];
}

// ---------------------------------------------------------------- GEMM (NT)
// C[m][n] = sum_k A[m][k]*B[n][k]  (row-major MxK / NxK, bf16 in)
// 128x128 tile, BK=32, 256 threads (2x2 waves, each 64x64 via 4x4 16x16x32).
// SPLITK: z -> (kc=z>>1, b=z&1), K = chunk len, C indexed by raw z.
// WINM:   z -> (wi=z>>1, b=z&1); offsets += wi*{aWw,bWw,cWw}; TRI row += wi*rowstep.
enum { EP_F32_SCALE = 0, EP_TRI_WRITE = 1, EP_TRI_ADD = 2, EP_BF16 = 3,
       EP_BF16_BIAS = 4, EP_SIG = 5, EP_F32_BIAS = 6, EP_F32_PART = 7 };

template<int EP, bool CQK, bool CKV, bool SPLITK, bool WINM>
__global__ __launch_bounds__(256) void gemm_nt(
    const unsigned short* __restrict__ A, int lda, long sAz, long aWw,
    const unsigned short* __restrict__ B, int ldb, long sBz, long bWw,
    void* Cv, int ldc, long sCz, long cWw,
    int K, float scale, const float* __restrict__ bias, int rowoff, int rowstep)
{
  const int mt = blockIdx.x, nt = blockIdx.y, z = blockIdx.z;
  if (CQK && nt > mt) return;  // causal: tile fully above diagonal
  __shared__ unsigned short As[4096];  // 128 x 32 bf16
  __shared__ unsigned short Bs[4096];
  const int tid = threadIdx.x;
  const int w = tid >> 6, lane = tid & 63;
  const int wm = w >> 1, wn = w & 1;
  const int lr = lane & 15, lk = lane >> 4;

  int zb = z, koff = 0, ro = rowoff;
  long aw = 0, bw = 0, cw = 0;
  if (SPLITK) { zb = z & 1; koff = (z >> 1) * K; }
  if (WINM) {
    zb = z & 1;
    const int wi = z >> 1;
    aw = (long)wi * aWw; bw = (long)wi * bWw; cw = (long)wi * cWw;
    ro += wi * rowstep;
  }

  const unsigned short* Ab = A + (long)zb * sAz + aw + (long)mt * 128 * lda + koff;
  const unsigned short* Bb = B + (long)zb * sBz + bw + (long)nt * 128 * ldb + koff;

  f32x4 acc[4][4];
  #pragma unroll
  for (int i = 0; i < 4; i++)
    #pragma unroll
    for (int j = 0; j < 4; j++)
      acc[i][j] = (f32x4){0.f, 0.f, 0.f, 0.f};

  int Keff = K;
  if (CKV) { int kl = (mt + 1) * 128; if (kl < Keff) Keff = kl; }
  const int nkt = Keff >> 5;

  for (int kt = 0; kt < nkt; ++kt) {
    #pragma unroll
    for (int i = 0; i < 2; i++) {
      const int c = tid + i * 256;
      const unsigned short* ga = Ab + (long)(c >> 2) * lda + kt * 32 + (c & 3) * 8;
      const unsigned short* gb = Bb + (long)(c >> 2) * ldb + kt * 32 + (c & 3) * 8;
      __builtin_amdgcn_global_load_lds((__attribute__((address_space(1))) void*)(void*)ga,
                                       (__attribute__((address_space(3))) void*)(As + c * 8), 16, 0, 0);
      __builtin_amdgcn_global_load_lds((__attribute__((address_space(1))) void*)(void*)gb,
                                       (__attribute__((address_space(3))) void*)(Bs + c * 8), 16, 0, 0);
    }
    __syncthreads();
    bf16x8 af[4], bfr[4];
    #pragma unroll
    for (int i = 0; i < 4; i++) {
      u16x8 ua = *(const u16x8*)&As[(wm * 64 + i * 16 + lr) * 32 + lk * 8];
      u16x8 ub = *(const u16x8*)&Bs[(wn * 64 + i * 16 + lr) * 32 + lk * 8];
      af[i] = __builtin_bit_cast(bf16x8, ua);
      bfr[i] = __builtin_bit_cast(bf16x8, ub);
    }
    #pragma unroll
    for (int i = 0; i < 4; i++)
      #pragma unroll
      for (int j = 0; j < 4; j++)
        acc[i][j] = __builtin_amdgcn_mfma_f32_16x16x32_bf16(af[i], bfr[j], acc[i][j], 0, 0, 0);
    __syncthreads();
  }

  // D layout: row=(lane>>4)*4+reg, col=lane&15 (m89-verified)
  const long zo = WINM ? ((long)zb * sCz + cw) : (long)z * sCz;
  const int r0 = mt * 128 + wm * 64;
  const int c0 = nt * 128 + wn * 64;
  #pragma unroll
  for (int i = 0; i < 4; i++)
    #pragma unroll
    for (int j = 0; j < 4; j++)
      #pragma unroll
      for (int r = 0; r < 4; r++) {
        const int row = r0 + i * 16 + lk * 4 + r;
        const int col = c0 + j * 16 + lr;
        const float v = acc[i][j][r];
        const long idx = zo + (long)row * ldc + col;
        if constexpr (EP == EP_F32_SCALE) {
          ((float*)Cv)[idx] = v * scale;
        } else if constexpr (EP == EP_TRI_WRITE || EP == EP_TRI_ADD) {
          const float inv2047 = 1.f / 2047.f;
          const int gs = ro + row, m = gs >> 10, rr = gs & 1023;
          float wsum = 0.f;
          if (m >= 1) wsum += 0.5f + (float)(rr + 1024) * inv2047;
          if (m <= 6) wsum += 0.5f + (float)rr * inv2047;
          const float wgt = (0.5f + (float)row * inv2047) / (wsum + 1e-6f);
          unsigned short* cp = (unsigned short*)Cv;
          if constexpr (EP == EP_TRI_WRITE) cp[idx] = f2bf(v * wgt);
          else                               cp[idx] = f2bf(bf2f(cp[idx]) + v * wgt);
        } else if constexpr (EP == EP_BF16) {
          ((unsigned short*)Cv)[idx] = f2bf(v);
        } else if constexpr (EP == EP_BF16_BIAS) {
          ((unsigned short*)Cv)[idx] = f2bf(v + bias[col]);
        } else if constexpr (EP == EP_SIG) {
          const float g = v + bias[col];
          ((unsigned short*)Cv)[idx] = f2bf(1.f / (1.f + __expf(-g)));
        } else if constexpr (EP == EP_F32_PART) {
          ((float*)Cv)[idx] = v;
        } else {
          ((float*)Cv)[idx] = v + bias[col];
        }
      }
}

// ------------------------------------------------------------- prep kernels
__global__ __launch_bounds__(256) void cast_bf_k(const float* __restrict__ in, unsigned short* __restrict__ out, long n) {
  long i = ((long)blockIdx.x * 256 + threadIdx.x) * 4;
  if (i >= n) return;
  f4 v = *(const f4*)&in[i];
  u16x4 o;
  #pragma unroll
  for (int j = 0; j < 4; j++) o[j] = f2bf(v[j]);
  *(u16x4*)&out[i] = o;
}

// Wc (o,d,k) -> W2[o][k*1024+d] bf16
__global__ __launch_bounds__(256) void wc2_k(const float* __restrict__ Wc, unsigned short* __restrict__ W2) {
  long i = (long)blockIdx.x * 256 + threadIdx.x;  // < 4,194,304
  int o = (int)(i >> 12), rem = (int)(i & 4095), k2 = rem >> 10, d = rem & 1023;
  W2[i] = f2bf(Wc[((long)o << 12) + (d << 2) + k2]);
}

// gm -> gt rows 128..255 (both batches)
__global__ __launch_bounds__(256) void gmfill_k(const float* __restrict__ gm, unsigned short* __restrict__ gt) {
  long i = (long)blockIdx.x * 256 + threadIdx.x;  // < 262,144
  int d = (int)(i & 1023), g = (int)((i >> 10) & 127), b = (int)(i >> 17);
  gt[((long)b * 256 + 128 + g) * 1024 + d] = f2bf(gm[(long)g * 1024 + d]);
}

// x (b,s,d) f32 -> xT (b,d,s) bf16
__global__ __launch_bounds__(256) void transp_xT_k(const float* __restrict__ x, unsigned short* __restrict__ xT) {
  __shared__ unsigned short tl[32][33];
  const int s0 = blockIdx.x * 32, d0 = blockIdx.y * 32;
  const long b = blockIdx.z;
  const int tx = threadIdx.x & 31, ty = threadIdx.x >> 5;
  const float* xb = x + b * 8388608;
  unsigned short* xtb = xT + b * 8388608;
  #pragma unroll
  for (int k = 0; k < 4; k++) tl[ty + k * 8][tx] = f2bf(xb[(long)(s0 + ty + k * 8) * 1024 + d0 + tx]);
  __syncthreads();
  #pragma unroll
  for (int k = 0; k < 4; k++) xtb[(long)(d0 + ty + k * 8) * 8192 + s0 + tx] = tl[tx][ty + k * 8];
}

// x (b,s,d) f32 -> xTf (b,d,s) f32 (for broadcast; runs after SWA)
__global__ __launch_bounds__(256) void transp_xf_k(const float* __restrict__ x, float* __restrict__ xTf) {
  __shared__ float tlf[32][33];
  const int s0 = blockIdx.x * 32, d0 = blockIdx.y * 32;
  const long b = blockIdx.z;
  const int tx = threadIdx.x & 31, ty = threadIdx.x >> 5;
  const float* xb = x + b * 8388608;
  float* xtf = xTf + b * 8388608;
  #pragma unroll
  for (int k = 0; k < 4; k++) tlf[ty + k * 8][tx] = xb[(long)(s0 + ty + k * 8) * 1024 + d0 + tx];
  __syncthreads();
  #pragma unroll
  for (int k = 0; k < 4; k++) xtf[(long)(d0 + ty + k * 8) * 8192 + s0 + tx] = tlf[tx][ty + k * 8];
}

// gt (b,256,1024) -> gtT (b,1024,256)
__global__ __launch_bounds__(256) void transp_gt_k(const unsigned short* __restrict__ gt, unsigned short* __restrict__ gtT) {
  __shared__ unsigned short tl[32][33];
  const int r0 = blockIdx.x * 32, c0 = blockIdx.y * 32;
  const long b = blockIdx.z;
  const int tx = threadIdx.x & 31, ty = threadIdx.x >> 5;
  const unsigned short* in = gt + b * 262144;
  unsigned short* out = gtT + b * 262144;
  #pragma unroll
  for (int k = 0; k < 4; k++) tl[ty + k * 8][tx] = in[(long)(r0 + ty + k * 8) * 1024 + c0 + tx];
  __syncthreads();
  #pragma unroll
  for (int k = 0; k < 4; k++) out[(long)(c0 + ty + k * 8) * 256 + r0 + tx] = tl[tx][ty + k * 8];
}

// ------------------------------------------------------------- softmaxes
// SWA: z = blockIdx.y selects (window,batch) slice; row q of 2048; causal.
__global__ __launch_bounds__(256) void smax_swa_k(const float* __restrict__ S, unsigned short* __restrict__ P) {
  const int q = blockIdx.x, t = threadIdx.x;
  const long zo = (long)blockIdx.y * 4194304;
  const float* row = S + zo + (long)q * 2048;
  unsigned short* prow = P + zo + (long)q * 2048;
  float e0[4], e1[4];
  float lsum = 0.f;
  const int k0 = t * 4, k1 = 1024 + t * 4;
  f4 v0 = *(const f4*)&row[k0];
  f4 v1 = *(const f4*)&row[k1];
  #pragma unroll
  for (int j = 0; j < 4; j++) { float e = (k0 + j <= q) ? __expf(v0[j]) : 0.f; e0[j] = e; lsum += e; }
  #pragma unroll
  for (int j = 0; j < 4; j++) { float e = (k1 + j <= q) ? __expf(v1[j]) : 0.f; e1[j] = e; lsum += e; }
  const float inv = 1.f / block_sum_256(lsum);
  u16x4 o0, o1;
  #pragma unroll
  for (int j = 0; j < 4; j++) { o0[j] = f2bf(e0[j] * inv); o1[j] = f2bf(e1[j] * inv); }
  *(u16x4*)&prow[k0] = o0;
  *(u16x4*)&prow[k1] = o1;
}

// global attn softmax: rows of 256
__global__ __launch_bounds__(256) void smax_g_k(const float* __restrict__ L, unsigned short* __restrict__ Pg) {
  const long row = blockIdx.x + (long)blockIdx.y * 8192;
  const int t = threadIdx.x;
  const float e = __expf(L[row * 256 + t]);
  const float tot = block_sum_256(e);
  Pg[row * 256 + t] = f2bf(e / tot);
}

// ------------------------------------------------------------- comp reduce
__global__ __launch_bounds__(256) void reduce_comp_k(const float* __restrict__ parts, const float* __restrict__ bc,
                                                     unsigned short* __restrict__ gt) {
  const int i = blockIdx.x * 256 + threadIdx.x;  // < 262144
  const int o = i & 1023, t = (i >> 10) & 127, b = i >> 17;
  float s = bc[o];
  #pragma unroll
  for (int kc = 0; kc < 8; kc++) s += parts[(long)(kc * 2 + b) * 131072 + t * 1024 + o];
  gt[((long)b * 256 + t) * 1024 + o] = f2bf(s);
}

// ------------------------------------------------------------- broadcast
// All 13 strides on one (b,d) column of 8192, in LDS, in-place on xTf.
__global__ __launch_bounds__(256) void bcast_col_k(float* __restrict__ col) {
  __shared__ float xs[8192];
  float* c = col + (long)blockIdx.x * 8192;
  const int t = threadIdx.x;
  float v[32], rs[32];
  #pragma unroll
  for (int j = 0; j < 32; j++) {
    v[j] = c[t + j * 256];
    xs[t + j * 256] = v[j];
    rs[j] = 0.f;
  }
  __syncthreads();
  for (int it = 0; it < 13; ++it) {
    const int st = 1 << it;
    float nv[32];
    #pragma unroll
    for (int j = 0; j < 32; j++) {
      const int e = t + j * 256;
      nv[j] = v[j] + 0.5f * (xs[(e - st) & 8191] + xs[(e + st) & 8191]);
    }
    __syncthreads();
    #pragma unroll
    for (int j = 0; j < 32; j++) {
      xs[t + j * 256] = nv[j];
      v[j] = nv[j];
      rs[j] += nv[j];
    }
    __syncthreads();
  }
  const float sc = 1.f / 14.f;  // log2(8192)+1
  #pragma unroll
  for (int j = 0; j < 32; j++) c[t + j * 256] = rs[j] * sc;
}

// ------------------------------------------------------------- final mix
// reads bcast result in transposed layout (b,d,s) via 32x32 LDS tile
__global__ __launch_bounds__(256) void mixed_t_k(const unsigned short* __restrict__ mw, const unsigned short* __restrict__ cat,
                                                 const float* __restrict__ rpT, unsigned short* __restrict__ mx) {
  __shared__ float tlf[32][36];
  const int s0 = blockIdx.x * 32, d0 = blockIdx.y * 32;
  const long b = blockIdx.z;
  const int t = threadIdx.x;
  const int tr = t >> 3, tc4 = (t & 7) * 4;
  *(f4*)&tlf[tr][tc4] = *(const f4*)&rpT[b * 8388608 + (long)(d0 + tr) * 8192 + s0 + tc4];
  __syncthreads();
  const long row = b * 8192 + s0 + tr;
  u16x4 mwv = *(const u16x4*)&mw[row * 1024 + d0 + tc4];
  u16x4 lv  = *(const u16x4*)&cat[row * 2048 + d0 + tc4];
  u16x4 gv  = *(const u16x4*)&cat[row * 2048 + 1024 + d0 + tc4];
  u16x4 o;
  #pragma unroll
  for (int j = 0; j < 4; j++) {
    const float m = bf2f(mwv[j]);
    o[j] = f2bf(m * bf2f(lv[j]) + (1.f - m) * bf2f(gv[j]) + tlf[tc4 + j][tr]);
  }
  *(u16x4*)&mx[row * 1024 + d0 + tc4] = o;
}

// ------------------------------------------------------------- launcher
extern "C" void kernel_launch(void* const* d_in, const int* in_sizes, int n_in,
                              void* d_out, int out_size, void* d_ws, size_t ws_size,
                              hipStream_t stream) {
  (void)in_sizes; (void)n_in; (void)out_size;
  if (ws_size < (size_t)251658240) return;  // 240 MB gate: fail clean, not fault
  const float* x  = (const float*)d_in[0];
  const float* gm = (const float*)d_in[1];
  const float* Wc = (const float*)d_in[2];
  const float* bc = (const float*)d_in[3];
  const float* Wm = (const float*)d_in[4];
  const float* bm = (const float*)d_in[5];
  const float* Wo = (const float*)d_in[6];
  const float* bo = (const float*)d_in[7];
  char* ws = (char*)d_ws;
  const long M = 1048576;

  unsigned short* xbf  = (unsigned short*)(ws + 0 * M);    // 32 MB
  unsigned short* xbfT = (unsigned short*)(ws + 32 * M);   // 32 MB
  unsigned short* cat  = (unsigned short*)(ws + 64 * M);   // 64 MB
  float*          parts= (float*)(ws + 128 * M);           // 8 MB   (phase C)
  float*          logit= (float*)(ws + 136 * M);           // 16 MB  (phase C)
  unsigned short* Pg   = (unsigned short*)(ws + 152 * M);  // 8 MB   (phase C)
  float*          S1   = (float*)(ws + 128 * M);           // 4x16 MB (SWA)
  unsigned short* P1   = (unsigned short*)(ws + 192 * M);  // 4x8 MB  (SWA)
  float*          xTf  = (float*)(ws + 128 * M);           // 64 MB  (phase F)
  unsigned short* wmb  = (unsigned short*)(ws + 224 * M);  // 4 MB
  unsigned short* wob  = (unsigned short*)(ws + 228 * M);  // 2 MB
  unsigned short* gt   = (unsigned short*)(ws + 230 * M);  // 1 MB
  unsigned short* gtT  = (unsigned short*)(ws + 231 * M);  // 1 MB
  unsigned short* wc2  = (unsigned short*)(ws + 232 * M);  // 8 MB
  unsigned short* mwb  = (unsigned short*)(ws + 32 * M);   // reuse xbfT
  unsigned short* mxb  = (unsigned short*)(ws + 0 * M);    // reuse xbf

  // A. casts / permutes
  cast_bf_k<<<16384, 256, 0, stream>>>(x, xbf, 16777216L);
  cast_bf_k<<<2048, 256, 0, stream>>>(Wm, wmb, 2097152L);
  cast_bf_k<<<1024, 256, 0, stream>>>(Wo, wob, 1048576L);
  wc2_k<<<16384, 256, 0, stream>>>(Wc, wc2);
  gmfill_k<<<1024, 256, 0, stream>>>(gm, gt);
  transp_xT_k<<<dim3(256, 32, 2), 256, 0, stream>>>(x, xbfT);

  // B. compressed global attention
  gemm_nt<EP_F32_PART, false, false, true, false><<<dim3(1, 8, 16), 256, 0, stream>>>(
      xbf, 4096, 8388608L, 0L, wc2, 4096, 0L, 0L, parts, 1024, 131072L, 0L, 512, 1.f, nullptr, 0, 0);
  reduce_comp_k<<<1024, 256, 0, stream>>>(parts, bc, gt);
  transp_gt_k<<<dim3(8, 32, 2), 256, 0, stream>>>(gt, gtT);
  gemm_nt<EP_F32_SCALE, false, false, false, false><<<dim3(64, 2, 2), 256, 0, stream>>>(
      xbf, 1024, 8388608L, 0L, gt, 1024, 262144L, 0L, logit, 256, 2097152L, 0L, 1024, 0.03125f, nullptr, 0, 0);
  smax_g_k<<<dim3(8192, 2), 256, 0, stream>>>(logit, Pg);
  gemm_nt<EP_BF16, false, false, false, false><<<dim3(64, 8, 2), 256, 0, stream>>>(
      Pg, 256, 2097152L, 0L, gtT, 256, 262144L, 0L, cat + 1024, 2048, 16777216L, 0L, 256, 1.f, nullptr, 0, 0);

  // C. sliding-window attention, batched: z = wi*2 + b; window n = n0 + wi*2.
  //    Rounds: even windows (TRI_WRITE) then odd (TRI_ADD; disjoint within round).
  const int rounds_n0[4] = {0, 4, 1, 5};
  const int rounds_nz[4] = {4, 4, 4, 2};
  for (int rix = 0; rix < 4; rix++) {
    const int n0 = rounds_n0[rix], nz = rounds_nz[rix];
    gemm_nt<EP_F32_SCALE, true, false, false, true><<<dim3(16, 16, nz), 256, 0, stream>>>(
        xbf + (long)n0 * 1048576, 1024, 8388608L, 2097152L,
        xbf + (long)n0 * 1048576, 1024, 8388608L, 2097152L,
        S1, 2048, 4194304L, 8388608L, 1024, 0.03125f, nullptr, 0, 0);
    smax_swa_k<<<dim3(2048, nz), 256, 0, stream>>>(S1, P1);
    if (rix < 2) {
      gemm_nt<EP_TRI_WRITE, false, true, false, true><<<dim3(16, 8, nz), 256, 0, stream>>>(
          P1, 2048, 4194304L, 8388608L,
          xbfT + (long)n0 * 1024, 8192, 8388608L, 2048L,
          cat + (long)n0 * 2097152, 2048, 16777216L, 4194304L, 2048, 1.f, nullptr, n0 * 1024, 2048);
    } else {
      gemm_nt<EP_TRI_ADD, false, true, false, true><<<dim3(16, 8, nz), 256, 0, stream>>>(
          P1, 2048, 4194304L, 8388608L,
          xbfT + (long)n0 * 1024, 8192, 8388608L, 2048L,
          cat + (long)n0 * 2097152, 2048, 16777216L, 4194304L, 2048, 1.f, nullptr, n0 * 1024, 2048);
    }
  }

  // D. gate gemm (xbfT dead -> mwb overlays it)
  gemm_nt<EP_SIG, false, false, false, false><<<dim3(128, 8, 1), 256, 0, stream>>>(
      cat, 2048, 0L, 0L, wmb, 2048, 0L, 0L, mwb, 1024, 0L, 0L, 2048, 1.f, bm, 0, 0);

  // E. information broadcast (S/P dead -> xTf overlays; in-place stencil)
  transp_xf_k<<<dim3(256, 32, 2), 256, 0, stream>>>(x, xTf);
  bcast_col_k<<<2048, 256, 0, stream>>>(xTf);

  // F. mix + output projection
  mixed_t_k<<<dim3(256, 32, 2), 256, 0, stream>>>(mwb, cat, xTf, mxb);
  gemm_nt<EP_F32_BIAS, false, false, false, false><<<dim3(128, 8, 1), 256, 0, stream>>>(
      mxb, 1024, 0L, 0L, wob, 1024, 0L, 0L, (float*)d_out, 1024, 0L, 0L, 1024, 1.f, bo, 0, 0);
}